// Round 1
// baseline (24647.545 us; speedup 1.0000x reference)
//
#include <hip/hip_runtime.h>
#include <hip/hip_bf16.h>

// Dims (compile-time)
#define SS 128   // src len
#define TT 128   // dst len
#define BB 64    // batch
#define EE 512   // embed
#define HH 512   // decoder hidden / encoder bidir concat
#define Hh 256   // encoder per-dir hidden

// ---------------------------------------------------------------------------
// Embedding gather: out[(s*B+b)*512 + e] = emb[toks[b*seqlen + s]*512 + e]
__global__ void k_embed(const float* __restrict__ emb, const int* __restrict__ toks,
                        float* __restrict__ out, int seqlen) {
  int s = blockIdx.x / BB, b = blockIdx.x % BB;
  int tok = toks[b * seqlen + s];
  const float4* src = (const float4*)(emb + (size_t)tok * EE);
  float4* dst = (float4*)(out + (size_t)blockIdx.x * EE);
  dst[threadIdx.x] = src[threadIdx.x];   // 128 threads * 4 floats = 512
}

// ---------------------------------------------------------------------------
// Tiled fp32 GEMM: C[m][n] = sum_k X[m*ldx+k] * W[n*ldw+koff+k] + b1[n] + b2[n]
// BM=BN=128, BK=16, 256 threads, 8x8 per thread.
__global__ __launch_bounds__(256) void k_gemm(
    const float* __restrict__ X, int ldx,
    const float* __restrict__ W, int ldw, int koff,
    const float* __restrict__ b1, const float* __restrict__ b2,
    float* __restrict__ C, int ldc, int K) {
  __shared__ float Xs[16][132];
  __shared__ float Ws[16][132];
  int m0 = blockIdx.y * 128, n0 = blockIdx.x * 128;
  int tx = threadIdx.x & 15, ty = threadIdx.x >> 4;
  float acc[8][8] = {};
  for (int k0 = 0; k0 < K; k0 += 16) {
    __syncthreads();
#pragma unroll
    for (int j = 0; j < 2; ++j) {
      int f4 = threadIdx.x + j * 256;
      int row = f4 >> 2, kc = (f4 & 3) * 4;
      float4 xv = *(const float4*)&X[(size_t)(m0 + row) * ldx + k0 + kc];
      Xs[kc + 0][row] = xv.x; Xs[kc + 1][row] = xv.y;
      Xs[kc + 2][row] = xv.z; Xs[kc + 3][row] = xv.w;
      float4 wv = *(const float4*)&W[(size_t)(n0 + row) * ldw + koff + k0 + kc];
      Ws[kc + 0][row] = wv.x; Ws[kc + 1][row] = wv.y;
      Ws[kc + 2][row] = wv.z; Ws[kc + 3][row] = wv.w;
    }
    __syncthreads();
#pragma unroll
    for (int kk = 0; kk < 16; ++kk) {
      float a[8], w[8];
      *(float4*)&a[0] = *(const float4*)&Xs[kk][ty * 8];
      *(float4*)&a[4] = *(const float4*)&Xs[kk][ty * 8 + 4];
      *(float4*)&w[0] = *(const float4*)&Ws[kk][tx * 8];
      *(float4*)&w[4] = *(const float4*)&Ws[kk][tx * 8 + 4];
#pragma unroll
      for (int i = 0; i < 8; ++i)
#pragma unroll
        for (int j = 0; j < 8; ++j)
          acc[i][j] += a[i] * w[j];
    }
  }
  int m = m0 + ty * 8, n = n0 + tx * 8;
  float bias[8];
#pragma unroll
  for (int j = 0; j < 8; ++j)
    bias[j] = (b1 ? b1[n + j] : 0.f) + (b2 ? b2[n + j] : 0.f);
  for (int i = 0; i < 8; ++i) {
#pragma unroll
    for (int j = 0; j < 8; ++j)
      C[(size_t)(m + i) * ldc + n + j] = acc[i][j] + bias[j];
  }
}

__device__ __forceinline__ float sigf(float x) { return 1.f / (1.f + __expf(-x)); }

// ---------------------------------------------------------------------------
// Encoder recurrent step, both directions. grid (64 hc, 2 dir), block 256 = 64b x 4h.
// G: precomputed gates [S*B][2048] (cols d*1024 + gate*256 + h), biases folded in.
// encH: [2 parity][2 dir][B][Hh], encC: [2 dir][B][Hh] (in-place).
__global__ __launch_bounds__(256) void k_enc_step(
    const float* __restrict__ G, const float* __restrict__ w_hh,
    float* __restrict__ encH, float* __restrict__ encC,
    float* __restrict__ lout, int t) {
  int d = blockIdx.y;
  int s = d ? (SS - 1 - t) : t;
  int p = t & 1;
  int b = threadIdx.x & 63, hl = threadIdx.x >> 6;
  int h = blockIdx.x * 4 + hl;
  __shared__ float xs[64][132];
  const float* hp = encH + (size_t)((p * 2 + d) * 64) * 256;
  const float* wr = w_hh + (size_t)d * 1024 * 256;
  const float* gp = G + (size_t)(s * 64 + b) * 2048 + d * 1024 + h;
  float acc[4];
  acc[0] = gp[0]; acc[1] = gp[256]; acc[2] = gp[512]; acc[3] = gp[768];
  for (int k0 = 0; k0 < 256; k0 += 128) {
    __syncthreads();
    for (int f4 = threadIdx.x; f4 < 64 * 32; f4 += 256) {
      int row = f4 >> 5, kc = (f4 & 31) * 4;
      *(float4*)&xs[row][kc] = *(const float4*)&hp[row * 256 + k0 + kc];
    }
    __syncthreads();
#pragma unroll 8
    for (int kk = 0; kk < 128; kk += 4) {
      float4 xv = *(const float4*)&xs[b][kk];
#pragma unroll
      for (int g = 0; g < 4; ++g) {
        float4 wv = *(const float4*)&wr[(size_t)(g * 256 + h) * 256 + k0 + kk];
        acc[g] += xv.x * wv.x + xv.y * wv.y + xv.z * wv.z + xv.w * wv.w;
      }
    }
  }
  float ig = sigf(acc[0]), fg = sigf(acc[1]), gv = tanhf(acc[2]), og = sigf(acc[3]);
  size_t ci = (size_t)(d * 64 + b) * 256 + h;
  float c = fg * encC[ci] + ig * gv;
  encC[ci] = c;
  float hn = og * tanhf(c);
  encH[(size_t)(((p ^ 1) * 2 + d) * 64 + b) * 256 + h] = hn;
  lout[(size_t)(s * 64 + b) * 512 + d * 256 + h] = hn;
}

// Copy encoder final states (parity pr) into decoder init [B][512] concat(fwd,bwd)
__global__ void k_copy_finals(const float* __restrict__ encH, const float* __restrict__ encC,
                              int pr, float* __restrict__ hdst, float* __restrict__ cdst) {
  int b = blockIdx.x, h = threadIdx.x;
  for (int d = 0; d < 2; ++d) {
    hdst[b * 512 + d * 256 + h] = encH[(size_t)((pr * 2 + d) * 64 + b) * 256 + h];
    cdst[b * 512 + d * 256 + h] = encC[(size_t)(d * 64 + b) * 256 + h];
  }
}

// ---------------------------------------------------------------------------
// Decoder LSTM cell (H=512): gates = pre + b1 + b2 + xa@Wa(cols coffa..)^T + xb@Wb^T
// grid 128 (h chunks of 4), block 256 = 64b x 4h. cbuf in-place; hout = new h buffer.
__global__ __launch_bounds__(256) void k_dec_cell(
    const float* __restrict__ pre, const float* __restrict__ b1, const float* __restrict__ b2,
    const float* __restrict__ xa, const float* __restrict__ Wa, int ldwa, int coffa,
    const float* __restrict__ xb, const float* __restrict__ Wb, int ldwb,
    float* __restrict__ cbuf, float* __restrict__ hout) {
  int b = threadIdx.x & 63, hl = threadIdx.x >> 6;
  int h = blockIdx.x * 4 + hl;
  __shared__ float xs[64][132];
  float acc[4];
#pragma unroll
  for (int g = 0; g < 4; ++g) {
    int j = g * 512 + h;
    float v = 0.f;
    if (pre) v += pre[b * 2048 + j];
    if (b1) v += b1[j] + b2[j];
    acc[g] = v;
  }
  for (int srcI = 0; srcI < 2; ++srcI) {
    const float* X = srcI ? xb : xa;
    const float* W = srcI ? Wb : Wa;
    int ldw = srcI ? ldwb : ldwa;
    int coff = srcI ? 0 : coffa;
    for (int k0 = 0; k0 < 512; k0 += 128) {
      __syncthreads();
      for (int f4 = threadIdx.x; f4 < 2048; f4 += 256) {
        int row = f4 >> 5, kc = (f4 & 31) * 4;
        *(float4*)&xs[row][kc] = *(const float4*)&X[row * 512 + k0 + kc];
      }
      __syncthreads();
#pragma unroll 4
      for (int kk = 0; kk < 128; kk += 4) {
        float4 xv = *(const float4*)&xs[b][kk];
#pragma unroll
        for (int g = 0; g < 4; ++g) {
          float4 wv = *(const float4*)&W[(size_t)(g * 512 + h) * ldw + coff + k0 + kk];
          acc[g] += xv.x * wv.x + xv.y * wv.y + xv.z * wv.z + xv.w * wv.w;
        }
      }
    }
  }
  float ig = sigf(acc[0]), fg = sigf(acc[1]), gv = tanhf(acc[2]), og = sigf(acc[3]);
  int ci = b * 512 + h;
  float c = fg * cbuf[ci] + ig * gv;
  cbuf[ci] = c;
  hout[ci] = og * tanhf(c);
}

// ---------------------------------------------------------------------------
// Attention for one decoder step: one block per batch b.
__global__ __launch_bounds__(256) void k_attn(
    const float* __restrict__ enc_out, const float* __restrict__ h1,
    const int* __restrict__ src_tokens, float* __restrict__ ctx) {
  int b = blockIdx.x, tid = threadIdx.x;
  __shared__ float h1s[512];
  __shared__ float sc[128];
  for (int i = tid; i < 512; i += 256) h1s[i] = h1[b * 512 + i];
  __syncthreads();
  {
    int s = tid >> 1, half = tid & 1;
    const float* er = enc_out + (size_t)(s * 64 + b) * 512 + half * 256;
    const float* hh = h1s + half * 256;
    float a = 0.f;
#pragma unroll 8
    for (int k = 0; k < 256; k += 4) {
      float4 ev = *(const float4*)&er[k];
      a += ev.x * hh[k] + ev.y * hh[k + 1] + ev.z * hh[k + 2] + ev.w * hh[k + 3];
    }
    a += __shfl_xor(a, 1);
    if (half == 0)
      sc[s] = (src_tokens[b * SS + s] == 0) ? -1e30f : a;
  }
  __syncthreads();
  if (tid < 64) {   // softmax over 128 scores, wave 0
    float m = fmaxf(sc[tid], sc[tid + 64]);
    for (int off = 32; off; off >>= 1) m = fmaxf(m, __shfl_xor(m, off));
    float e0 = __expf(sc[tid] - m), e1 = __expf(sc[tid + 64] - m);
    float ssum = e0 + e1;
    for (int off = 32; off; off >>= 1) ssum += __shfl_xor(ssum, off);
    float inv = 1.f / ssum;
    sc[tid] = e0 * inv; sc[tid + 64] = e1 * inv;
  }
  __syncthreads();
  float a0 = 0.f, a1 = 0.f;
  for (int s = 0; s < 128; ++s) {
    float p = sc[s];
    const float* er = enc_out + (size_t)(s * 64 + b) * 512;
    a0 += p * er[tid];
    a1 += p * er[tid + 256];
  }
  ctx[b * 512 + tid] = a0;
  ctx[b * 512 + tid + 256] = a1;
}

// ---------------------------------------------------------------------------
// out = tanh([ctx, h1] @ attn_w^T); writes feed (input-feeding) + houts[t].
// grid 128 (o chunks of 4), block 256 = 64b x 4o.
__global__ __launch_bounds__(256) void k_outproj(
    const float* __restrict__ ctx, const float* __restrict__ h1,
    const float* __restrict__ aw, float* __restrict__ feed, float* __restrict__ houtT) {
  int b = threadIdx.x & 63, ol = threadIdx.x >> 6;
  int o = blockIdx.x * 4 + ol;
  __shared__ float xs[64][132];
  float acc = 0.f;
  for (int srcI = 0; srcI < 2; ++srcI) {
    const float* X = srcI ? h1 : ctx;
    int coff = srcI * 512;
    for (int k0 = 0; k0 < 512; k0 += 128) {
      __syncthreads();
      for (int f4 = threadIdx.x; f4 < 2048; f4 += 256) {
        int row = f4 >> 5, kc = (f4 & 31) * 4;
        *(float4*)&xs[row][kc] = *(const float4*)&X[row * 512 + k0 + kc];
      }
      __syncthreads();
#pragma unroll 4
      for (int kk = 0; kk < 128; kk += 4) {
        float4 xv = *(const float4*)&xs[b][kk];
        float4 wv = *(const float4*)&aw[(size_t)o * 1024 + coff + k0 + kk];
        acc += xv.x * wv.x + xv.y * wv.y + xv.z * wv.z + xv.w * wv.w;
      }
    }
  }
  float v = tanhf(acc);
  feed[b * 512 + o] = v;
  houtT[b * 512 + o] = v;
}

// ---------------------------------------------------------------------------
// res[b][o][t] = in[(t*64+b)*512 + o]; grid (64 b, 4 t-tiles, 8 o-tiles)
__global__ __launch_bounds__(256) void k_transpose(const float* __restrict__ in,
                                                   float* __restrict__ out) {
  __shared__ float xs[32][65];
  int b = blockIdx.x, t0 = blockIdx.y * 32, n0 = blockIdx.z * 64;
  int j = threadIdx.x & 63, i0 = threadIdx.x >> 6;
  for (int r = 0; r < 8; ++r) {
    int ti = i0 * 8 + r;
    xs[ti][j & 31] = 0;  // placeholder to silence warnings (overwritten below)
    xs[ti][j - ((j >> 5) << 5)] = xs[ti][j - ((j >> 5) << 5)];
  }
  // proper load: tile is 32 t x 64 n, but xs is [32][65] -> stage in two n-halves
  for (int halfn = 0; halfn < 2; ++halfn) {
    __syncthreads();
    for (int r = 0; r < 4; ++r) {
      int ti = i0 * 8 + r * 2 + 0;   // 8 rows per i0 over 2 sub-iterations
      int ti2 = i0 * 8 + r * 2 + 1;
      if (j < 32) {
        xs[ti][j] = in[(size_t)((t0 + ti) * 64 + b) * 512 + n0 + halfn * 32 + j];
        xs[ti2][j + 32] = 0;  // unused slot guard
      } else {
        xs[ti2][j - 32] = in[(size_t)((t0 + ti2) * 64 + b) * 512 + n0 + halfn * 32 + (j - 32)];
      }
    }
    __syncthreads();
    int ttl = threadIdx.x & 31, ng = threadIdx.x >> 5;
    for (int r = 0; r < 4; ++r) {
      int nl = ng * 4 + r;
      out[(size_t)b * (512 * 128) + (size_t)(n0 + halfn * 32 + nl) * 128 + t0 + ttl] = xs[ttl][nl];
    }
  }
}

// ---------------------------------------------------------------------------
extern "C" void kernel_launch(void* const* d_in, const int* in_sizes, int n_in,
                              void* d_out, int out_size, void* d_ws, size_t ws_size,
                              hipStream_t stream) {
  const int*   src_tokens = (const int*)d_in[0];
  const int*   dst        = (const int*)d_in[2];
  const float* emb_in     = (const float*)d_in[3];
  const float* emb_out    = (const float*)d_in[4];
  const float* enc_w_ih0  = (const float*)d_in[5];
  const float* enc_w_ih1  = (const float*)d_in[6];
  const float* enc_w_hh   = (const float*)d_in[7];
  const float* enc_b_ih   = (const float*)d_in[8];
  const float* enc_b_hh   = (const float*)d_in[9];
  const float* dec_w_ih0  = (const float*)d_in[10];
  const float* dec_w_hh0  = (const float*)d_in[11];
  const float* dec_b_ih0  = (const float*)d_in[12];
  const float* dec_b_hh0  = (const float*)d_in[13];
  const float* dec_w_ih1  = (const float*)d_in[14];
  const float* dec_w_hh1  = (const float*)d_in[15];
  const float* dec_b_ih1  = (const float*)d_in[16];
  const float* dec_b_hh1  = (const float*)d_in[17];
  const float* attn_w     = (const float*)d_in[18];
  const float* pred_w     = (const float*)d_in[19];
  const float* pred_b     = (const float*)d_in[20];
  float* out = (float*)d_out;

  float* ws     = (float*)d_ws;
  float* bufA   = ws;               // 4,194,304 f  (x0 / l0out / dst_emb)
  float* G      = ws + 4194304;     // 16,777,216 f (gates / final tmp)
  float* encOut = ws + 20971520;    // 4,194,304 f
  float* houts  = ws + 25165824;    // 4,194,304 f
  float* encH   = ws + 29360128;    // 65,536 f [2par][2dir][64][256]
  float* encC   = ws + 29425664;    // 32,768 f
  float* h0     = ws + 29458432;    // 65,536 f (2 parity)
  float* c0     = ws + 29523968;    // 32,768 f
  float* h1     = ws + 29556736;    // 65,536 f
  float* c1     = ws + 29622272;    // 32,768 f
  float* feed   = ws + 29655040;    // 32,768 f
  float* ctx    = ws + 29687808;    // 32,768 f

  // ---- Encoder ----
  k_embed<<<dim3(SS * BB), 128, 0, stream>>>(emb_in, src_tokens, bufA, SS);
  for (int l = 0; l < 2; ++l) {
    const float* wih = l ? enc_w_ih1 : enc_w_ih0;   // [2][1024][512] -> [2048][512]
    k_gemm<<<dim3(16, 64), 256, 0, stream>>>(bufA, 512, wih, 512, 0,
                                             enc_b_ih + l * 2048, enc_b_hh + l * 2048,
                                             G, 2048, 512);
    hipMemsetAsync(encH, 0, 2 * 64 * 256 * sizeof(float), stream);  // parity 0
    hipMemsetAsync(encC, 0, 2 * 64 * 256 * sizeof(float), stream);
    float* lo = l ? encOut : bufA;
    const float* whh = enc_w_hh + (size_t)l * 2 * 1024 * 256;
    for (int t = 0; t < SS; ++t)
      k_enc_step<<<dim3(64, 2), 256, 0, stream>>>(G, whh, encH, encC, lo, t);
    k_copy_finals<<<dim3(64), 256, 0, stream>>>(encH, encC, 0, l ? h1 : h0, l ? c1 : c0);
  }

  // ---- Decoder precompute: emb-part of layer-0 gates ----
  k_embed<<<dim3(TT * BB), 128, 0, stream>>>(emb_out, dst, bufA, TT);
  k_gemm<<<dim3(16, 64), 256, 0, stream>>>(bufA, 512, dec_w_ih0, 1024, 0,
                                           dec_b_ih0, dec_b_hh0, G, 2048, 512);
  hipMemsetAsync(feed, 0, 64 * 512 * sizeof(float), stream);

  // ---- Decoder steps ----
  for (int t = 0; t < TT; ++t) {
    int p = t & 1;
    k_dec_cell<<<dim3(128), 256, 0, stream>>>(
        G + (size_t)t * 64 * 2048, nullptr, nullptr,
        feed, dec_w_ih0, 1024, 512,
        h0 + p * 32768, dec_w_hh0, 512,
        c0, h0 + (p ^ 1) * 32768);
    k_dec_cell<<<dim3(128), 256, 0, stream>>>(
        nullptr, dec_b_ih1, dec_b_hh1,
        h0 + (p ^ 1) * 32768, dec_w_ih1, 512, 0,
        h1 + p * 32768, dec_w_hh1, 512,
        c1, h1 + (p ^ 1) * 32768);
    k_attn<<<dim3(64), 256, 0, stream>>>(encOut, h1 + (p ^ 1) * 32768, src_tokens, ctx);
    k_outproj<<<dim3(128), 256, 0, stream>>>(ctx, h1 + (p ^ 1) * 32768, attn_w,
                                             feed, houts + (size_t)t * 32768);
  }

  // ---- Final projection + transpose to [B][OUT][T] ----
  k_gemm<<<dim3(4, 64), 256, 0, stream>>>(houts, 512, pred_w, 512, 0,
                                          pred_b, nullptr, G, 512, 512);
  k_transpose<<<dim3(64, 4, 8), 256, 0, stream>>>(G, out);
}